// Round 5
// baseline (148.411 us; speedup 1.0000x reference)
//
#include <hip/hip_runtime.h>
#include <cstdint>
#include <cstddef>

#define WDIM 1600
#define BDIM 4
#define HDIM 900
#define NV4  225   // float4s per column (900/4)
#define QCAP 96    // max valid radar entries per column (mean ~27, sigma ~5.1)
#define KBIG (4 * HDIM)
#define BW   8     // query batch width (phase A)
#define NWAVE 4    // columns (waves) per workgroup

// wave64 min via DPP: after the 6 steps lane 63 holds the full-wave min.
// Canonical GCN cross-lane reduction (row_shr 1/2/4/8, row_bcast15/31).
// old = v (lanes with invalid DPP source keep v => min(v,v) no-op).
#define DPP_MINF(v, ctrl)                                                  \
    v = fminf(v, __int_as_float(__builtin_amdgcn_update_dpp(               \
            __float_as_int(v), __float_as_int(v), ctrl, 0xf, 0xf, false)))

#define DPP_MINI(v, ctrl)                                                  \
    { int _dt = __builtin_amdgcn_update_dpp(v, v, ctrl, 0xf, 0xf, false);  \
      v = (_dt < v) ? _dt : v; }

// Wave-local LDS fence: waves in this WG never share LDS (each owns its
// s_*_all[wv] slice); __syncthreads would couple independent columns to the
// slowest of 4 (R2: 58->70us, E[max4]). Same-wave LDS ordering only needs
// lgkmcnt(0) + a compiler memory fence.
#define WAVE_FENCE() asm volatile("s_waitcnt lgkmcnt(0)" ::: "memory")

// Phase 1: one wave per (w,b) column; NWAVE independent columns per WG.
// NOTE: (256, 4) not (256, 8): min-waves=8 capped the VGPR budget and spilled
// to scratch (VGPR 44->32, WRITE_SIZE 22.6->74.6 MB, R1).
// R4/R5 restructure: argmin for ALL queries first (phase A, dense VALU, fully
// pipelined; results deposited in s_qy, which is dead after A when has_mde),
// then a tight serial placement loop (phase B, readlane-based). R3's fused
// loop alternated 500cy scan with 600cy serial cross-lane chain -> 45% idle.
// (No __builtin_amdgcn_writelane on this toolchain -- R4 compile fail.)
__global__ __launch_bounds__(256, 4) void radar_place_kernel(
    const float* __restrict__ radar, const float* __restrict__ mde,
    float* __restrict__ colout /* (W*B, H) */, int direct, float* __restrict__ out)
{
    __shared__ __align__(16) float s_col_all[NWAVE][HDIM];
    __shared__ float s_qd_all[NWAVE][QCAP];
    __shared__ int   s_qy_all[NWAVE][QCAP];

    const int lane = threadIdx.x & 63;     // 0..63 within wave
    const int wv   = threadIdx.x >> 6;     // 0..NWAVE-1
    const int colid = blockIdx.x * NWAVE + wv;   // 0..W*B-1

    float* s_col = s_col_all[wv];
    float* s_qd  = s_qd_all[wv];
    int*   s_qy  = s_qy_all[wv];

    const float4* mde4   = (const float4*)mde   + (long)colid * NV4;
    const float4* radar4 = (const float4*)radar + (long)colid * NV4;
    float4* col4 = (float4*)s_col;

    const unsigned long long below = (1ull << lane) - 1ull;

    // --- A1: coalesced mde load -> stash raw into s_col (used as scratch) ---
    bool hm = false;
#pragma unroll
    for (int c = 0; c < 4; ++c) {
        int i4 = c * 64 + lane;
        if (i4 < NV4) {
            float4 mv = mde4[i4];
            hm = hm || (mv.x != 0.f) || (mv.y != 0.f) || (mv.z != 0.f) || (mv.w != 0.f);
            col4[i4] = mv;
        }
    }
    const bool has_mde = (__ballot(hm) != 0ull);

    // --- A2: radar load + ascending-y compaction into s_qd/s_qy ---
    int Q = 0;
#pragma unroll
    for (int c = 0; c < 4; ++c) {
        int i4 = c * 64 + lane;
        bool in = (i4 < NV4);
        float4 rv = in ? radar4[i4] : make_float4(0.f, 0.f, 0.f, 0.f);
        unsigned long long b0 = __ballot(rv.x != 0.f);
        unsigned long long b1 = __ballot(rv.y != 0.f);
        unsigned long long b2 = __ballot(rv.z != 0.f);
        unsigned long long b3 = __ballot(rv.w != 0.f);
        int pos = Q + __popcll(b0 & below) + __popcll(b1 & below)
                    + __popcll(b2 & below) + __popcll(b3 & below);
        int y0 = i4 * 4;
        if (rv.x != 0.f) { if (pos < QCAP) { s_qd[pos] = rv.x; s_qy[pos] = y0;     } pos++; }
        if (rv.y != 0.f) { if (pos < QCAP) { s_qd[pos] = rv.y; s_qy[pos] = y0 + 1; } pos++; }
        if (rv.z != 0.f) { if (pos < QCAP) { s_qd[pos] = rv.z; s_qy[pos] = y0 + 2; } pos++; }
        if (rv.w != 0.f) { if (pos < QCAP) { s_qd[pos] = rv.w; s_qy[pos] = y0 + 3; } pos++; }
        Q += __popcll(b0) + __popcll(b1) + __popcll(b2) + __popcll(b3);
    }
    if (Q > QCAP) Q = QCAP;

    WAVE_FENCE();   // A1 s_col writes complete before A3 reads (same wave only)

    // --- A3: redistribute mde lane-major: lane l owns y = l*15 + k (900 = 60*15) ---
    float m[15];
    if (lane < 60) {
        int yb = lane * 15;
#pragma unroll
        for (int k = 0; k < 15; ++k) {
            float v = s_col[yb + k];       // addr = 15*l + k: 15 odd => conflict-free
            m[k] = (v != 0.f) ? v : 1e30f; // invalid mde -> BIG diff
        }
    } else {
#pragma unroll
        for (int k = 0; k < 15; ++k) m[k] = 1e30f;
    }

    WAVE_FENCE();   // A3 reads complete before A4 zeroing (WAR, same wave)

    // --- A4: zero output column ---
#pragma unroll
    for (int c = 0; c < 4; ++c) {
        int i4 = c * 64 + lane;
        if (i4 < NV4) col4[i4] = make_float4(0.f, 0.f, 0.f, 0.f);
    }

    // ===================== Phase A: argmin for ALL queries =====================
    // s_qy[q] <- best y for query q (s_qy is dead after this when has_mde;
    // when !has_mde s_qy already holds the right answer: the radar's own y).
    // No serial state -> scans and per-query extraction chains fully pipeline.
    if (has_mde) {
        for (int t = 0; t < Q; t += BW) {
            float d[BW];
#pragma unroll
            for (int i = 0; i < BW; ++i) {
                int idx = (t + i < Q) ? (t + i) : (Q - 1);
                d[i] = s_qd[idx];          // wave-uniform broadcast LDS read
            }
            float bd[BW], bo[BW];
            int bik[BW];
#pragma unroll
            for (int i = 0; i < BW; ++i) { bd[i] = 3.4e38f; bik[i] = 0; }
            // per-lane scan over its 15 contiguous y; k ascending => first k kept
#pragma unroll
            for (int k = 0; k < 15; ++k) {
                float mm = m[k];
#pragma unroll
                for (int i = 0; i < BW; ++i) {
                    float af = fabsf(mm - d[i]);
                    if (af < bd[i]) { bd[i] = af; bik[i] = k; }
                }
            }
#pragma unroll
            for (int i = 0; i < BW; ++i) bo[i] = bd[i];
#pragma unroll
            for (int i = 0; i < BW; ++i) DPP_MINF(bd[i], 0x111);
#pragma unroll
            for (int i = 0; i < BW; ++i) DPP_MINF(bd[i], 0x112);
#pragma unroll
            for (int i = 0; i < BW; ++i) DPP_MINF(bd[i], 0x114);
#pragma unroll
            for (int i = 0; i < BW; ++i) DPP_MINF(bd[i], 0x118);
#pragma unroll
            for (int i = 0; i < BW; ++i) DPP_MINF(bd[i], 0x142);
#pragma unroll
            for (int i = 0; i < BW; ++i) DPP_MINF(bd[i], 0x143);

#pragma unroll
            for (int i = 0; i < BW; ++i) {
                // first lane holding global min; its first-k => global first y
                // (lanes 60-63 have bo ~1e30 > gm, never win when has_mde)
                float gm = __int_as_float(
                    __builtin_amdgcn_readlane(__float_as_int(bd[i]), 63));
                unsigned long long wm = __ballot(bo[i] == gm);
                int win = __ffsll((long long)wm) - 1;
                int yall = lane * 15 + bik[i];
                int sy = __builtin_amdgcn_readlane(yall, win);
                // deposit: t+i <= ((Q-1)&~7)+7 <= 95 < QCAP always
                if (lane == 0) s_qy[t + i] = sy;   // fire-and-forget ds_write
            }
        }
    }

    WAVE_FENCE();   // phase-A s_qy deposits visible to the reloads below

    // lane q <-> query q register views for the serial loop
    const int hi_idx = (64 + lane < QCAP) ? (64 + lane) : (QCAP - 1);
    int   by0 = s_qy[lane];
    int   by1 = s_qy[hi_idx];
    float dp0 = s_qd[lane];
    float dp1 = s_qd[hi_idx];

    // ===================== Phase B: serial placement =====================
    // occupancy: bit k of lane l <=> y = l*15+k occupied; lanes >= 60 inert
    unsigned occ = (lane >= 60) ? 0x7FFFu : 0u;

    auto place = [&](int sb, float depth) {
        int bl = sb / 15, bk = sb % 15;                     // uniform (SALU)
        // occupancy test: single readlane + scalar bit test (no ballot chain)
        unsigned ob = (unsigned)__builtin_amdgcn_readlane((int)occ, bl);
        int fy = sb;
        if ((ob >> bk) & 1u) {
            // slow path (rare): key = occ ? BIG : 2|dy|+(dy<0); key is
            // injective below KBIG (distinct y -> distinct dy) so the DPP min
            // is the unique winner and final_y decodes directly from the key.
            int ko = 0x7fffffff;
#pragma unroll
            for (int k = 0; k < 15; ++k) {
                int yy = lane * 15 + k;
                int o = (occ >> k) & 1;
                int dy = yy - sb;
                int ad = dy < 0 ? -dy : dy;
                int key = 2 * ad + (dy < 0 ? 1 : 0);
                int pk = o ? 0x7fffffff : key;
                ko = (pk < ko) ? pk : ko;
            }
            DPP_MINI(ko, 0x111);
            DPP_MINI(ko, 0x112);
            DPP_MINI(ko, 0x114);
            DPP_MINI(ko, 0x118);
            DPP_MINI(ko, 0x142);
            DPP_MINI(ko, 0x143);
            int kmin = __builtin_amdgcn_readlane(ko, 63);
            if (kmin < KBIG)
                fy = sb + ((kmin & 1) ? -(kmin >> 1) : (kmin >> 1));
            // else: column full (impossible here, Q<=96<900) -> overwrite sb
        }
        int fl = fy / 15, fk = fy % 15;                     // uniform
        occ |= (lane == fl) ? (1u << fk) : 0u;              // branchless update
        if (lane == 0) s_col[fy] = depth;  // unique slots; same-wave DS order
    };

    const int qe = (Q < 64) ? Q : 64;
    for (int q = 0; q < qe; ++q) {
        int sb = __builtin_amdgcn_readlane(by0, q);
        float dv = __int_as_float(__builtin_amdgcn_readlane(__float_as_int(dp0), q));
        place(sb, dv);
    }
    for (int q = 64; q < Q; ++q) {
        int sb = __builtin_amdgcn_readlane(by1, q - 64);
        float dv = __int_as_float(__builtin_amdgcn_readlane(__float_as_int(dp1), q - 64));
        place(sb, dv);
    }

    WAVE_FENCE();   // drain placement writes before readback (same wave)

    // --- writeout ---
    if (direct) {
        int w_ = colid >> 2, b_ = colid & 3;
#pragma unroll
        for (int c = 0; c < 4; ++c) {
            int i4 = c * 64 + lane;
            if (i4 < NV4) {
                float4 v = col4[i4];
                int y = i4 * 4;
                out[((long)(b_ * HDIM + y + 0)) * WDIM + w_] = v.x;
                out[((long)(b_ * HDIM + y + 1)) * WDIM + w_] = v.y;
                out[((long)(b_ * HDIM + y + 2)) * WDIM + w_] = v.z;
                out[((long)(b_ * HDIM + y + 3)) * WDIM + w_] = v.w;
            }
        }
    } else {
        float4* colout4 = (float4*)colout + (long)colid * NV4;
#pragma unroll
        for (int c = 0; c < 4; ++c) {
            int i4 = c * 64 + lane;
            if (i4 < NV4) colout4[i4] = col4[i4];
        }
    }
}

// Phase 2: transpose (W*B, H) -> (B, H, W), fully coalesced both sides.
__global__ __launch_bounds__(256) void transpose_kernel(
    const float* __restrict__ colout, float* __restrict__ out)
{
    __shared__ float tile[32][33];
    const int b  = blockIdx.z;
    const int h0 = blockIdx.x * 32;
    const int w0 = blockIdx.y * 32;
    const int tx = threadIdx.x & 31;
    const int ty = threadIdx.x >> 5;  // 0..7
#pragma unroll
    for (int j = 0; j < 4; ++j) {
        int wl = ty + j * 8;
        int w = w0 + wl;
        int h = h0 + tx;
        float v = 0.0f;
        if (h < HDIM && w < WDIM) v = colout[((long)(w * BDIM + b)) * HDIM + h];
        tile[wl][tx] = v;
    }
    __syncthreads();
#pragma unroll
    for (int j = 0; j < 4; ++j) {
        int hl = ty + j * 8;
        int h = h0 + hl;
        int w = w0 + tx;
        if (h < HDIM && w < WDIM)
            out[((long)(b * HDIM + h)) * WDIM + w] = tile[tx][hl];
    }
}

extern "C" void kernel_launch(void* const* d_in, const int* in_sizes, int n_in,
                              void* d_out, int out_size, void* d_ws, size_t ws_size,
                              hipStream_t stream) {
    const float* radar = (const float*)d_in[0];
    const float* mde   = (const float*)d_in[1];
    float* out = (float*)d_out;
    float* ws  = (float*)d_ws;

    const size_t need = (size_t)WDIM * BDIM * HDIM * sizeof(float);
    const int direct = (ws_size < need) ? 1 : 0;

    hipLaunchKernelGGL(radar_place_kernel,
                       dim3(WDIM * BDIM / NWAVE), dim3(64 * NWAVE), 0, stream,
                       radar, mde, ws, direct, out);

    if (!direct) {
        dim3 g((HDIM + 31) / 32, WDIM / 32, BDIM);
        hipLaunchKernelGGL(transpose_kernel, g, dim3(256), 0, stream, ws, out);
    }
}

// Round 6
// 133.486 us; speedup vs baseline: 1.1118x; 1.1118x over previous
//
#include <hip/hip_runtime.h>
#include <cstdint>
#include <cstddef>

#define WDIM 1600
#define BDIM 4
#define HDIM 900
#define NV4  225   // float4s per column (900/4)
#define QCAP 96    // max valid radar entries per column (mean ~27, sigma ~5.1)
#define KBIG (4 * HDIM)
#define BW   8     // query batch width
#define NWAVE 4    // columns (waves) per workgroup

// wave64 min via DPP: after the 6 steps lane 63 holds the full-wave min.
// Canonical GCN cross-lane reduction (row_shr 1/2/4/8, row_bcast15/31).
// old = v (lanes with invalid DPP source keep v => min(v,v) no-op).
#define DPP_MINF(v, ctrl)                                                  \
    v = fminf(v, __int_as_float(__builtin_amdgcn_update_dpp(               \
            __float_as_int(v), __float_as_int(v), ctrl, 0xf, 0xf, false)))

#define DPP_MINI(v, ctrl)                                                  \
    { int _dt = __builtin_amdgcn_update_dpp(v, v, ctrl, 0xf, 0xf, false);  \
      v = (_dt < v) ? _dt : v; }

// Wave-local LDS fence: waves in this WG never share LDS (each owns its
// s_*_all[wv] slice); __syncthreads would couple independent columns to the
// slowest of 4 (R2: 58->70us, E[max4]). Same-wave LDS ordering only needs
// lgkmcnt(0) + a compiler memory fence.
#define WAVE_FENCE() asm volatile("s_waitcnt lgkmcnt(0)" ::: "memory")

// Phase 1: one wave per (w,b) column; NWAVE independent columns per WG.
// Structure: fused argmin+placement per batch (R3, proven 58us). R5's A/B
// split regressed (68us): extraction chain paid twice + LDS round trip.
// Kernel is ISSUE-bound (VALUBusy ~55%, extra waves don't help: R0==R3) =>
// this revision only removes instructions from the per-query serial tail:
//   - readlane(bik, win) instead of ds_bpermute shfl; best goes scalar
//   - occupancy probe = readlane(occ, bl) + scalar bit test (no ballot)
//   - occ update via in-range arithmetic on laneY (no div, no readfirstlane)
//   - placement ds_write from all lanes (same addr+data), no exec dance
// NOTE: (256, 4) not (256, 8): min-waves=8 capped the VGPR budget and
// spilled to scratch (VGPR 44->32, WRITE_SIZE 22.6->74.6 MB, R1).
__global__ __launch_bounds__(256, 4) void radar_place_kernel(
    const float* __restrict__ radar, const float* __restrict__ mde,
    float* __restrict__ colout /* (W*B, H) */, int direct, float* __restrict__ out)
{
    __shared__ __align__(16) float s_col_all[NWAVE][HDIM];
    __shared__ float s_qd_all[NWAVE][QCAP];
    __shared__ int   s_qy_all[NWAVE][QCAP];

    const int lane = threadIdx.x & 63;     // 0..63 within wave
    const int wv   = threadIdx.x >> 6;     // 0..NWAVE-1
    const int colid = blockIdx.x * NWAVE + wv;   // 0..W*B-1

    float* s_col = s_col_all[wv];
    float* s_qd  = s_qd_all[wv];
    int*   s_qy  = s_qy_all[wv];

    const float4* mde4   = (const float4*)mde   + (long)colid * NV4;
    const float4* radar4 = (const float4*)radar + (long)colid * NV4;
    float4* col4 = (float4*)s_col;

    const unsigned long long below = (1ull << lane) - 1ull;
    const int laneY = lane * 15;           // first y owned by this lane

    // --- A1: coalesced mde load -> stash raw into s_col (used as scratch) ---
    bool hm = false;
#pragma unroll
    for (int c = 0; c < 4; ++c) {
        int i4 = c * 64 + lane;
        if (i4 < NV4) {
            float4 mv = mde4[i4];
            hm = hm || (mv.x != 0.f) || (mv.y != 0.f) || (mv.z != 0.f) || (mv.w != 0.f);
            col4[i4] = mv;
        }
    }
    const bool has_mde = (__ballot(hm) != 0ull);

    // --- A2: radar load + ascending-y compaction into s_qd/s_qy ---
    int Q = 0;
#pragma unroll
    for (int c = 0; c < 4; ++c) {
        int i4 = c * 64 + lane;
        bool in = (i4 < NV4);
        float4 rv = in ? radar4[i4] : make_float4(0.f, 0.f, 0.f, 0.f);
        unsigned long long b0 = __ballot(rv.x != 0.f);
        unsigned long long b1 = __ballot(rv.y != 0.f);
        unsigned long long b2 = __ballot(rv.z != 0.f);
        unsigned long long b3 = __ballot(rv.w != 0.f);
        int pos = Q + __popcll(b0 & below) + __popcll(b1 & below)
                    + __popcll(b2 & below) + __popcll(b3 & below);
        int y0 = i4 * 4;
        if (rv.x != 0.f) { if (pos < QCAP) { s_qd[pos] = rv.x; s_qy[pos] = y0;     } pos++; }
        if (rv.y != 0.f) { if (pos < QCAP) { s_qd[pos] = rv.y; s_qy[pos] = y0 + 1; } pos++; }
        if (rv.z != 0.f) { if (pos < QCAP) { s_qd[pos] = rv.z; s_qy[pos] = y0 + 2; } pos++; }
        if (rv.w != 0.f) { if (pos < QCAP) { s_qd[pos] = rv.w; s_qy[pos] = y0 + 3; } pos++; }
        Q += __popcll(b0) + __popcll(b1) + __popcll(b2) + __popcll(b3);
    }
    if (Q > QCAP) Q = QCAP;

    WAVE_FENCE();   // A1 s_col writes complete before A3 reads (same wave only)

    // --- A3: redistribute mde lane-major: lane l owns y = l*15 + k (900 = 60*15) ---
    float m[15];
    if (lane < 60) {
#pragma unroll
        for (int k = 0; k < 15; ++k) {
            float v = s_col[laneY + k];    // addr = 15*l + k: 15 odd => conflict-free
            m[k] = (v != 0.f) ? v : 1e30f; // invalid mde -> BIG diff
        }
    } else {
#pragma unroll
        for (int k = 0; k < 15; ++k) m[k] = 1e30f;
    }

    WAVE_FENCE();   // A3 reads complete before A4 zeroing (WAR, same wave)

    // --- A4: zero output column ---
#pragma unroll
    for (int c = 0; c < 4; ++c) {
        int i4 = c * 64 + lane;
        if (i4 < NV4) col4[i4] = make_float4(0.f, 0.f, 0.f, 0.f);
    }

    // occupancy: bit k of lane l <=> y = l*15+k occupied; lanes >= 60 inert
    unsigned occ = (lane >= 60) ? 0x7FFFu : 0u;

    // --- fused argmin + placement, BW queries per batch ---
    for (int t = 0; t < Q; t += BW) {
        float d[BW];
#pragma unroll
        for (int i = 0; i < BW; ++i) {
            int idx = (t + i < Q) ? (t + i) : (Q - 1);
            d[i] = s_qd[idx];              // wave-uniform broadcast LDS read
        }
        float bd[BW], bo[BW];
        int bik[BW];
#pragma unroll
        for (int i = 0; i < BW; ++i) { bd[i] = 3.4e38f; bik[i] = 0; }
        // per-lane scan over its 15 contiguous y: k ascending => first index kept
#pragma unroll
        for (int k = 0; k < 15; ++k) {
            float mm = m[k];
#pragma unroll
            for (int i = 0; i < BW; ++i) {
                float af = fabsf(mm - d[i]);
                if (af < bd[i]) { bd[i] = af; bik[i] = k; }
            }
        }
#pragma unroll
        for (int i = 0; i < BW; ++i) bo[i] = bd[i];
        // wave-wide f32 min via DPP (6 VALU steps, BW interleaved); min -> lane 63
#pragma unroll
        for (int i = 0; i < BW; ++i) DPP_MINF(bd[i], 0x111);
#pragma unroll
        for (int i = 0; i < BW; ++i) DPP_MINF(bd[i], 0x112);
#pragma unroll
        for (int i = 0; i < BW; ++i) DPP_MINF(bd[i], 0x114);
#pragma unroll
        for (int i = 0; i < BW; ++i) DPP_MINF(bd[i], 0x118);
#pragma unroll
        for (int i = 0; i < BW; ++i) DPP_MINF(bd[i], 0x142);
#pragma unroll
        for (int i = 0; i < BW; ++i) DPP_MINF(bd[i], 0x143);

        // --- per-query tie-break + placement (short scalar-heavy tail) ---
#pragma unroll
        for (int i = 0; i < BW; ++i) {
            if (t + i < Q) {               // wave-uniform branch (cheap skip)
                int sy;
                if (has_mde) {
                    float gm = __int_as_float(
                        __builtin_amdgcn_readlane(__float_as_int(bd[i]), 63));
                    // first lane holding global min; its first-k => first y.
                    // (lanes 60-63 have bo ~1e30 > gm, never win when has_mde)
                    unsigned long long wm = __ballot(bo[i] == gm);
                    int win = __ffsll((long long)wm) - 1;          // SGPR
                    int kst = __builtin_amdgcn_readlane(bik[i], win);
                    sy = win * 15 + kst;                           // uniform
                } else {
                    sy = s_qy[t + i];
                }
                float depth = d[i];
                int bl = sy / 15, bk = sy % 15;                    // scalar magic-div
                unsigned ob = (unsigned)__builtin_amdgcn_readlane((int)occ, bl);
                int fy = sy;
                if ((ob >> bk) & 1u) {
                    // slow path (rare): key = occ ? BIG : 2|dy|+(dy<0); key is
                    // injective below KBIG (distinct y -> distinct dy) so the
                    // min is unique and final_y decodes directly from the key.
                    int ko = 0x7fffffff;
#pragma unroll
                    for (int k = 0; k < 15; ++k) {
                        int yy = laneY + k;
                        int o = (occ >> k) & 1;
                        int dy = yy - sy;
                        int ad = dy < 0 ? -dy : dy;
                        int key = 2 * ad + (dy < 0 ? 1 : 0);
                        int pk = o ? 0x7fffffff : key;
                        ko = (pk < ko) ? pk : ko;
                    }
                    DPP_MINI(ko, 0x111);
                    DPP_MINI(ko, 0x112);
                    DPP_MINI(ko, 0x114);
                    DPP_MINI(ko, 0x118);
                    DPP_MINI(ko, 0x142);
                    DPP_MINI(ko, 0x143);
                    int kmin = __builtin_amdgcn_readlane(ko, 63);
                    if (kmin < KBIG)
                        fy = sy + ((kmin & 1) ? -(kmin >> 1) : (kmin >> 1));
                    // else: column full (impossible, Q<=96<900) -> overwrite sy
                }
                // occ update: branchless in-range arithmetic (no div, no cmp-eq
                // against a scalar-divided lane id)
                unsigned fk = (unsigned)(fy - laneY);
                occ |= (fk < 15u) ? (1u << fk) : 0u;
                // placement: all lanes store same value to same address
                // (same-address LDS write = single commit, no serialization)
                s_col[fy] = depth;
            }
        }
    }

    WAVE_FENCE();   // drain placement writes before readback (same wave)

    // --- writeout ---
    if (direct) {
        int w_ = colid >> 2, b_ = colid & 3;
#pragma unroll
        for (int c = 0; c < 4; ++c) {
            int i4 = c * 64 + lane;
            if (i4 < NV4) {
                float4 v = col4[i4];
                int y = i4 * 4;
                out[((long)(b_ * HDIM + y + 0)) * WDIM + w_] = v.x;
                out[((long)(b_ * HDIM + y + 1)) * WDIM + w_] = v.y;
                out[((long)(b_ * HDIM + y + 2)) * WDIM + w_] = v.z;
                out[((long)(b_ * HDIM + y + 3)) * WDIM + w_] = v.w;
            }
        }
    } else {
        float4* colout4 = (float4*)colout + (long)colid * NV4;
#pragma unroll
        for (int c = 0; c < 4; ++c) {
            int i4 = c * 64 + lane;
            if (i4 < NV4) colout4[i4] = col4[i4];
        }
    }
}

// Phase 2: transpose (W*B, H) -> (B, H, W), fully coalesced both sides.
__global__ __launch_bounds__(256) void transpose_kernel(
    const float* __restrict__ colout, float* __restrict__ out)
{
    __shared__ float tile[32][33];
    const int b  = blockIdx.z;
    const int h0 = blockIdx.x * 32;
    const int w0 = blockIdx.y * 32;
    const int tx = threadIdx.x & 31;
    const int ty = threadIdx.x >> 5;  // 0..7
#pragma unroll
    for (int j = 0; j < 4; ++j) {
        int wl = ty + j * 8;
        int w = w0 + wl;
        int h = h0 + tx;
        float v = 0.0f;
        if (h < HDIM && w < WDIM) v = colout[((long)(w * BDIM + b)) * HDIM + h];
        tile[wl][tx] = v;
    }
    __syncthreads();
#pragma unroll
    for (int j = 0; j < 4; ++j) {
        int hl = ty + j * 8;
        int h = h0 + hl;
        int w = w0 + tx;
        if (h < HDIM && w < WDIM)
            out[((long)(b * HDIM + h)) * WDIM + w] = tile[tx][hl];
    }
}

extern "C" void kernel_launch(void* const* d_in, const int* in_sizes, int n_in,
                              void* d_out, int out_size, void* d_ws, size_t ws_size,
                              hipStream_t stream) {
    const float* radar = (const float*)d_in[0];
    const float* mde   = (const float*)d_in[1];
    float* out = (float*)d_out;
    float* ws  = (float*)d_ws;

    const size_t need = (size_t)WDIM * BDIM * HDIM * sizeof(float);
    const int direct = (ws_size < need) ? 1 : 0;

    hipLaunchKernelGGL(radar_place_kernel,
                       dim3(WDIM * BDIM / NWAVE), dim3(64 * NWAVE), 0, stream,
                       radar, mde, ws, direct, out);

    if (!direct) {
        dim3 g((HDIM + 31) / 32, WDIM / 32, BDIM);
        hipLaunchKernelGGL(transpose_kernel, g, dim3(256), 0, stream, ws, out);
    }
}